// Round 1
// baseline (2344.232 us; speedup 1.0000x reference)
//
#include <hip/hip_runtime.h>
#include <cstdint>

// TransformerClassification: B=32, S=1024, E=1024, FF=1024, OUT=2, 2 identical blocks.
// Outputs (fp32, concat flat): logits[32,2] (64), w1[32,1024,1024], w2[32,1024,1024].
// Strategy: bf16 MFMA GEMMs (m97-style gemm_bt: 128x128 tile, BK=64, global_load_lds
// width 16), fp32 residual stream, fused epilogues (bias / relu / residual / V-transpose
// / score-scale). LN + softmax as block-per-row reduction kernels.

#define AS1 __attribute__((address_space(1)))
#define AS3 __attribute__((address_space(3)))

typedef __attribute__((ext_vector_type(8))) short bf16x8;
typedef __attribute__((ext_vector_type(4))) float f32x4;
typedef __attribute__((ext_vector_type(4))) unsigned short us4;

__device__ __forceinline__ unsigned short f2bf(float f) {
  unsigned int u = __builtin_bit_cast(unsigned int, f);
  u += 0x7fffu + ((u >> 16) & 1u);          // round-to-nearest-even
  return (unsigned short)(u >> 16);
}

__device__ __forceinline__ void gload_lds16(const void* g, void* l) {
  auto gp = reinterpret_cast<AS1 unsigned int*>(reinterpret_cast<uintptr_t>(g));
  auto lp = reinterpret_cast<AS3 unsigned int*>(reinterpret_cast<uintptr_t>(l));
  __builtin_amdgcn_global_load_lds(gp, lp, 16, 0, 0);
}

enum { M_BF16 = 0, M_RELU = 1, M_VT = 2, M_SCORES = 3, M_RESID = 4 };

// C = A (MxK, bf16, row-major) * B^T (B is NxK, bf16, row-major), batched via blockIdx.z.
// 128x128 tile, 256 threads = 4 waves, each wave a 64x64 quadrant (4x4 MFMA tiles).
template<int MODE>
__global__ __launch_bounds__(256, 2) void gemm_bt(
    const unsigned short* __restrict__ A, long long sAb,
    const unsigned short* __restrict__ B, long long sBb,
    const float* __restrict__ bias,
    const float* __restrict__ resid,
    float* __restrict__ outF,
    unsigned short* __restrict__ outBF,
    long long sOb, int N, int K, float scale)
{
  __shared__ __align__(16) unsigned short As[128 * 64];
  __shared__ __align__(16) unsigned short Bs[128 * 64];
  const int t    = threadIdx.x;
  const int w    = t >> 6;
  const int lane = t & 63;
  const int quad = lane >> 4;
  const int l16  = lane & 15;
  const int bz   = blockIdx.z;
  const unsigned short* Ab = A + (long long)bz * sAb;
  const unsigned short* Bb = B + (long long)bz * sBb;
  const int m0 = blockIdx.y * 128;
  const int n0 = blockIdx.x * 128;
  const int srow = t >> 3;          // row within a 32-row staging chunk
  const int scol = (t & 7) * 8;     // bf16 column of the 16B segment
  const int wr = (w >> 1) * 64;     // wave quadrant
  const int wc = (w & 1) * 64;

  const f32x4 zero = {0.f, 0.f, 0.f, 0.f};
  f32x4 acc[4][4];
#pragma unroll
  for (int i = 0; i < 4; ++i)
#pragma unroll
    for (int j = 0; j < 4; ++j) acc[i][j] = zero;

  for (int k0 = 0; k0 < K; k0 += 64) {
#pragma unroll
    for (int c = 0; c < 4; ++c) {
      // LDS dest: wave-uniform base; HW adds lane*16B -> exactly [row][col] layout.
      gload_lds16(Ab + (long long)(m0 + c * 32 + srow) * K + (k0 + scol),
                  As + c * 2048 + w * 512);
      gload_lds16(Bb + (long long)(n0 + c * 32 + srow) * K + (k0 + scol),
                  Bs + c * 2048 + w * 512);
    }
    __syncthreads();
#pragma unroll
    for (int kk = 0; kk < 64; kk += 32) {
      bf16x8 af[4], bfr[4];
#pragma unroll
      for (int i = 0; i < 4; ++i)
        af[i] = *(const bf16x8*)&As[(wr + i * 16 + l16) * 64 + kk + quad * 8];
#pragma unroll
      for (int j = 0; j < 4; ++j)
        bfr[j] = *(const bf16x8*)&Bs[(wc + j * 16 + l16) * 64 + kk + quad * 8];
#pragma unroll
      for (int i = 0; i < 4; ++i)
#pragma unroll
        for (int j = 0; j < 4; ++j)
          acc[i][j] = __builtin_amdgcn_mfma_f32_16x16x32_bf16(af[i], bfr[j], acc[i][j], 0, 0, 0);
    }
    __syncthreads();
  }

  // C/D layout: col = lane&15, row = quad*4 + reg
#pragma unroll
  for (int i = 0; i < 4; ++i) {
#pragma unroll
    for (int j = 0; j < 4; ++j) {
      const int mt = m0 + wr + i * 16 + quad * 4;
      const int nt = n0 + wc + j * 16 + l16;
      f32x4 d = acc[i][j];
      if (MODE == M_BF16 || MODE == M_RELU) {
        const float bv = bias ? bias[nt] : 0.0f;
#pragma unroll
        for (int r = 0; r < 4; ++r) {
          float v = d[r] + bv;
          if (MODE == M_RELU) v = fmaxf(v, 0.0f);
          outBF[(long long)bz * sOb + (long long)(mt + r) * N + nt] = f2bf(v);
        }
      } else if (MODE == M_SCORES) {
#pragma unroll
        for (int r = 0; r < 4; ++r)
          outF[(long long)bz * sOb + (long long)(mt + r) * N + nt] = d[r] * scale;
      } else if (MODE == M_RESID) {
        const float bv = bias[nt];
#pragma unroll
        for (int r = 0; r < 4; ++r) {
          const long long idx = (long long)(mt + r) * N + nt;
          outF[idx] = resid[idx] + d[r] + bv;
        }
      } else if (MODE == M_VT) {
        // V projection written transposed per batch: vT[b][d=nt][s=mt&1023]
        const float bv = bias[nt];
        us4 pk;
#pragma unroll
        for (int r = 0; r < 4; ++r) pk[r] = f2bf(d[r] + bv);
        const int b = mt >> 10;
        const int s = mt & 1023;
        *(us4*)&outBF[(long long)b * 1048576 + (long long)nt * 1024 + s] = pk;
      }
    }
  }
}

// LayerNorm over rows of 1024. EMBED=1: v = 32*x + pe written to x1out; else read xin.
template<int EMBED>
__global__ __launch_bounds__(256) void ln_kernel(
    const float* __restrict__ xin, const float* __restrict__ pe,
    float* __restrict__ x1out,
    const float* __restrict__ g, const float* __restrict__ bb,
    unsigned short* __restrict__ hout)
{
  __shared__ float red[8];
  const long long row = blockIdx.x;
  const int t = threadIdx.x, lane = t & 63, w = t >> 6;
  float4 v = *(const float4*)(xin + row * 1024 + t * 4);
  if (EMBED) {
    const int s = (int)(row & 1023);
    float4 p = *(const float4*)(pe + (long long)s * 1024 + t * 4);
    v.x = 32.0f * v.x + p.x;
    v.y = 32.0f * v.y + p.y;
    v.z = 32.0f * v.z + p.z;
    v.w = 32.0f * v.w + p.w;
    *(float4*)(x1out + row * 1024 + t * 4) = v;
  }
  float sum = v.x + v.y + v.z + v.w;
  float sq  = v.x * v.x + v.y * v.y + v.z * v.z + v.w * v.w;
#pragma unroll
  for (int off = 32; off > 0; off >>= 1) {
    sum += __shfl_down(sum, off, 64);
    sq  += __shfl_down(sq,  off, 64);
  }
  if (lane == 0) { red[w] = sum; red[4 + w] = sq; }
  __syncthreads();
  sum = red[0] + red[1] + red[2] + red[3];
  sq  = red[4] + red[5] + red[6] + red[7];
  const float mu  = sum * (1.0f / 1024.0f);
  const float var = sq * (1.0f / 1024.0f) - mu * mu;
  const float rs  = rsqrtf(var + 1e-5f);
  float4 gg = *(const float4*)(g + t * 4);
  float4 bv = *(const float4*)(bb + t * 4);
  us4 h;
  h[0] = f2bf((v.x - mu) * rs * gg.x + bv.x);
  h[1] = f2bf((v.y - mu) * rs * gg.y + bv.y);
  h[2] = f2bf((v.z - mu) * rs * gg.z + bv.z);
  h[3] = f2bf((v.w - mu) * rs * gg.w + bv.w);
  *(us4*)(hout + row * 1024 + t * 4) = h;
}

// In-place softmax over rows of 1024 (fp32 in d_out slot) + bf16 copy for the PV GEMM.
__global__ __launch_bounds__(256) void softmax_kernel(
    float* __restrict__ wio, unsigned short* __restrict__ wbf)
{
  __shared__ float red[8];
  const long long row = blockIdx.x;
  const int t = threadIdx.x, lane = t & 63, w = t >> 6;
  float* p = wio + row * 1024 + t * 4;
  float4 v = *(const float4*)p;
  float mx = fmaxf(fmaxf(v.x, v.y), fmaxf(v.z, v.w));
#pragma unroll
  for (int off = 32; off > 0; off >>= 1) mx = fmaxf(mx, __shfl_down(mx, off, 64));
  if (lane == 0) red[w] = mx;
  __syncthreads();
  mx = fmaxf(fmaxf(red[0], red[1]), fmaxf(red[2], red[3]));
  __syncthreads();
  const float e0 = __expf(v.x - mx), e1 = __expf(v.y - mx);
  const float e2 = __expf(v.z - mx), e3 = __expf(v.w - mx);
  float s = e0 + e1 + e2 + e3;
#pragma unroll
  for (int off = 32; off > 0; off >>= 1) s += __shfl_down(s, off, 64);
  if (lane == 0) red[w] = s;
  __syncthreads();
  s = red[0] + red[1] + red[2] + red[3];
  const float inv = 1.0f / s;
  float4 o; o.x = e0 * inv; o.y = e1 * inv; o.z = e2 * inv; o.w = e3 * inv;
  *(float4*)p = o;
  us4 ob;
  ob[0] = f2bf(o.x); ob[1] = f2bf(o.y); ob[2] = f2bf(o.z); ob[3] = f2bf(o.w);
  *(us4*)(wbf + row * 1024 + t * 4) = ob;
}

__global__ __launch_bounds__(256) void cvt_bf16_kernel(
    const float* __restrict__ src, unsigned short* __restrict__ dst, int n4)
{
  const int i = blockIdx.x * 256 + threadIdx.x;
  if (i < n4) {
    float4 v = *(const float4*)(src + (long long)i * 4);
    us4 o;
    o[0] = f2bf(v.x); o[1] = f2bf(v.y); o[2] = f2bf(v.z); o[3] = f2bf(v.w);
    *(us4*)(dst + (long long)i * 4) = o;
  }
}

// logits[b,o] = x[b, s=0, :] . Wc[o,:] + bc[o]; 64 blocks, fp32.
__global__ __launch_bounds__(256) void logits_kernel(
    const float* __restrict__ x, const float* __restrict__ Wc,
    const float* __restrict__ bc, float* __restrict__ out)
{
  __shared__ float red[4];
  const int blk = blockIdx.x;           // b*2 + o
  const int b = blk >> 1, o = blk & 1;
  const int t = threadIdx.x, lane = t & 63, w = t >> 6;
  const float* xr = x + (long long)b * 1048576;
  const float* wr = Wc + o * 1024;
  float4 xv = *(const float4*)(xr + t * 4);
  float4 wv = *(const float4*)(wr + t * 4);
  float s = xv.x * wv.x + xv.y * wv.y + xv.z * wv.z + xv.w * wv.w;
#pragma unroll
  for (int off = 32; off > 0; off >>= 1) s += __shfl_down(s, off, 64);
  if (lane == 0) red[w] = s;
  __syncthreads();
  if (t == 0) out[blk] = red[0] + red[1] + red[2] + red[3] + bc[o];
}

extern "C" void kernel_launch(void* const* d_in, const int* in_sizes, int n_in,
                              void* d_out, int out_size, void* d_ws, size_t ws_size,
                              hipStream_t stream)
{
  const float* x    = (const float*)d_in[0];
  const float* pe   = (const float*)d_in[1];
  const float* ln1g = (const float*)d_in[2];
  const float* ln1b = (const float*)d_in[3];
  const float* Wq   = (const float*)d_in[4];
  const float* bq   = (const float*)d_in[5];
  const float* Wk   = (const float*)d_in[6];
  const float* bk   = (const float*)d_in[7];
  const float* Wv   = (const float*)d_in[8];
  const float* bv   = (const float*)d_in[9];
  const float* Wo   = (const float*)d_in[10];
  const float* bo   = (const float*)d_in[11];
  const float* ln2g = (const float*)d_in[12];
  const float* ln2b = (const float*)d_in[13];
  const float* W1   = (const float*)d_in[14];
  const float* b1   = (const float*)d_in[15];
  const float* W2   = (const float*)d_in[16];
  const float* b2   = (const float*)d_in[17];
  const float* Wc   = (const float*)d_in[18];
  const float* bc   = (const float*)d_in[19];
  float* out = (float*)d_out;

  // Workspace layout (needs ~396 MiB)
  char* ws = (char*)d_ws;
  float*          xbuf  = (float*)ws;                                         // 128 MiB residual stream
  unsigned short* h_bf  = (unsigned short*)(ws + 134217728LL);                // 64 MiB
  unsigned short* q_bf  = (unsigned short*)(ws + 134217728LL + 1*67108864LL); // also attn0
  unsigned short* k_bf  = (unsigned short*)(ws + 134217728LL + 2*67108864LL); // also w_bf
  unsigned short* vT_bf = (unsigned short*)(ws + 134217728LL + 3*67108864LL); // also ff1
  unsigned short* wts   = (unsigned short*)(ws + 134217728LL + 4*67108864LL); // 12 MiB
  unsigned short* Wq_bf = wts + 0LL * 1048576;
  unsigned short* Wk_bf = wts + 1LL * 1048576;
  unsigned short* Wv_bf = wts + 2LL * 1048576;
  unsigned short* Wo_bf = wts + 3LL * 1048576;
  unsigned short* W1_bf = wts + 4LL * 1048576;
  unsigned short* W2_bf = wts + 5LL * 1048576;
  unsigned short* attn_bf = q_bf;
  unsigned short* w_bf    = k_bf;
  unsigned short* ff1_bf  = vT_bf;

  const dim3 blk(256);
  // Weight conversions (must run every call; inputs re-restored each launch)
  cvt_bf16_kernel<<<1024, blk, 0, stream>>>(Wq, Wq_bf, 262144);
  cvt_bf16_kernel<<<1024, blk, 0, stream>>>(Wk, Wk_bf, 262144);
  cvt_bf16_kernel<<<1024, blk, 0, stream>>>(Wv, Wv_bf, 262144);
  cvt_bf16_kernel<<<1024, blk, 0, stream>>>(Wo, Wo_bf, 262144);
  cvt_bf16_kernel<<<1024, blk, 0, stream>>>(W1, W1_bf, 262144);
  cvt_bf16_kernel<<<1024, blk, 0, stream>>>(W2, W2_bf, 262144);

  const dim3 gProj(8, 256, 1);   // N=1024, M=32768
  const dim3 gAttn(8, 8, 32);    // N=M=1024, batch=32

  for (int blkI = 0; blkI < 2; ++blkI) {
    float* wslot = out + 64 + (long long)blkI * 33554432LL;

    if (blkI == 0)
      ln_kernel<1><<<32768, blk, 0, stream>>>(x, pe, xbuf, ln1g, ln1b, h_bf);
    else
      ln_kernel<0><<<32768, blk, 0, stream>>>(xbuf, nullptr, nullptr, ln1g, ln1b, h_bf);

    gemm_bt<M_BF16><<<gProj, blk, 0, stream>>>(h_bf, 0, Wq_bf, 0, bq, nullptr,
                                               nullptr, q_bf, 0, 1024, 1024, 1.0f);
    gemm_bt<M_BF16><<<gProj, blk, 0, stream>>>(h_bf, 0, Wk_bf, 0, bk, nullptr,
                                               nullptr, k_bf, 0, 1024, 1024, 1.0f);
    gemm_bt<M_VT><<<gProj, blk, 0, stream>>>(h_bf, 0, Wv_bf, 0, bv, nullptr,
                                             nullptr, vT_bf, 0, 1024, 1024, 1.0f);

    gemm_bt<M_SCORES><<<gAttn, blk, 0, stream>>>(q_bf, 1048576, k_bf, 1048576, nullptr,
                                                 nullptr, wslot, nullptr, 1048576,
                                                 1024, 1024, 0.03125f);
    softmax_kernel<<<32768, blk, 0, stream>>>(wslot, w_bf);

    gemm_bt<M_BF16><<<gAttn, blk, 0, stream>>>(w_bf, 1048576, vT_bf, 1048576, nullptr,
                                               nullptr, nullptr, attn_bf, 1048576,
                                               1024, 1024, 1.0f);
    gemm_bt<M_RESID><<<gProj, blk, 0, stream>>>(attn_bf, 0, Wo_bf, 0, bo, xbuf,
                                                xbuf, nullptr, 0, 1024, 1024, 1.0f);

    ln_kernel<0><<<32768, blk, 0, stream>>>(xbuf, nullptr, nullptr, ln2g, ln2b, h_bf);
    gemm_bt<M_RELU><<<gProj, blk, 0, stream>>>(h_bf, 0, W1_bf, 0, b1, nullptr,
                                               nullptr, ff1_bf, 0, 1024, 1024, 1.0f);
    gemm_bt<M_RESID><<<gProj, blk, 0, stream>>>(ff1_bf, 0, W2_bf, 0, b2, xbuf,
                                                xbuf, nullptr, 0, 1024, 1024, 1.0f);
  }

  logits_kernel<<<64, blk, 0, stream>>>(xbuf, Wc, bc, out);
  (void)in_sizes; (void)n_in; (void)out_size; (void)ws_size;
}

// Round 2
// 2244.959 us; speedup vs baseline: 1.0442x; 1.0442x over previous
//
#include <hip/hip_runtime.h>
#include <cstdint>

// TransformerClassification: B=32, S=1024, E=1024, FF=1024, OUT=2, 2 identical blocks.
// Outputs (fp32, concat flat): logits[32,2] (64), w1[32,1024,1024], w2[32,1024,1024].
// R2: fused QKV GEMM (N=3072, packed weights), bf16 scores path, single prep kernel,
// __launch_bounds__(256,3) for 3 blocks/CU.

#define AS1 __attribute__((address_space(1)))
#define AS3 __attribute__((address_space(3)))

typedef __attribute__((ext_vector_type(8))) short bf16x8;
typedef __attribute__((ext_vector_type(4))) float f32x4;
typedef __attribute__((ext_vector_type(4))) unsigned short us4;

__device__ __forceinline__ unsigned short f2bf(float f) {
  unsigned int u = __builtin_bit_cast(unsigned int, f);
  u += 0x7fffu + ((u >> 16) & 1u);          // round-to-nearest-even
  return (unsigned short)(u >> 16);
}
__device__ __forceinline__ float bf2f(unsigned short h) {
  return __builtin_bit_cast(float, (unsigned int)h << 16);
}

__device__ __forceinline__ void gload_lds16(const void* g, void* l) {
  auto gp = reinterpret_cast<AS1 unsigned int*>(reinterpret_cast<uintptr_t>(g));
  auto lp = reinterpret_cast<AS3 unsigned int*>(reinterpret_cast<uintptr_t>(l));
  __builtin_amdgcn_global_load_lds(gp, lp, 16, 0, 0);
}

enum { M_BF16 = 0, M_RELU = 1, M_QKV = 2, M_SCBF = 3, M_RESID = 4 };

// C = A (MxK, bf16, row-major) * B^T (B is NxK, bf16, row-major), batched via blockIdx.z.
// 128x128 tile, 256 threads = 4 waves, each wave a 64x64 quadrant (4x4 MFMA 16x16x32).
template<int MODE>
__global__ __launch_bounds__(256, 3) void gemm_bt(
    const unsigned short* __restrict__ A, long long sAb,
    const unsigned short* __restrict__ B, long long sBb,
    const float* __restrict__ bias,
    const float* __restrict__ resid,
    float* __restrict__ outF,
    unsigned short* __restrict__ outBF,
    long long sOb, int N, int K, float scale)
{
  __shared__ __align__(16) unsigned short As[128 * 64];
  __shared__ __align__(16) unsigned short Bs[128 * 64];
  const int t    = threadIdx.x;
  const int w    = t >> 6;
  const int lane = t & 63;
  const int quad = lane >> 4;
  const int l16  = lane & 15;
  const int bz   = blockIdx.z;
  const unsigned short* Ab = A + (long long)bz * sAb;
  const unsigned short* Bb = B + (long long)bz * sBb;
  const int m0 = blockIdx.y * 128;
  const int n0 = blockIdx.x * 128;
  const int srow = t >> 3;          // row within a 32-row staging chunk
  const int scol = (t & 7) * 8;     // bf16 column of the 16B segment
  const int wr = (w >> 1) * 64;     // wave quadrant
  const int wc = (w & 1) * 64;

  const f32x4 zero = {0.f, 0.f, 0.f, 0.f};
  f32x4 acc[4][4];
#pragma unroll
  for (int i = 0; i < 4; ++i)
#pragma unroll
    for (int j = 0; j < 4; ++j) acc[i][j] = zero;

  for (int k0 = 0; k0 < K; k0 += 64) {
#pragma unroll
    for (int c = 0; c < 4; ++c) {
      // LDS dest: wave-uniform base; HW adds lane*16B -> exactly [row][col] layout.
      gload_lds16(Ab + (long long)(m0 + c * 32 + srow) * K + (k0 + scol),
                  As + c * 2048 + w * 512);
      gload_lds16(Bb + (long long)(n0 + c * 32 + srow) * K + (k0 + scol),
                  Bs + c * 2048 + w * 512);
    }
    __syncthreads();
#pragma unroll
    for (int kk = 0; kk < 64; kk += 32) {
      bf16x8 af[4], bfr[4];
#pragma unroll
      for (int i = 0; i < 4; ++i)
        af[i] = *(const bf16x8*)&As[(wr + i * 16 + l16) * 64 + kk + quad * 8];
#pragma unroll
      for (int j = 0; j < 4; ++j)
        bfr[j] = *(const bf16x8*)&Bs[(wc + j * 16 + l16) * 64 + kk + quad * 8];
#pragma unroll
      for (int i = 0; i < 4; ++i)
#pragma unroll
        for (int j = 0; j < 4; ++j)
          acc[i][j] = __builtin_amdgcn_mfma_f32_16x16x32_bf16(af[i], bfr[j], acc[i][j], 0, 0, 0);
    }
    __syncthreads();
  }

  // C/D layout: col = lane&15, row = quad*4 + reg
#pragma unroll
  for (int i = 0; i < 4; ++i) {
#pragma unroll
    for (int j = 0; j < 4; ++j) {
      const int mt = m0 + wr + i * 16 + quad * 4;
      const int nt = n0 + wc + j * 16 + l16;
      f32x4 d = acc[i][j];
      if (MODE == M_BF16 || MODE == M_RELU) {
        const float bv = bias ? bias[nt] : 0.0f;
#pragma unroll
        for (int r = 0; r < 4; ++r) {
          float v = d[r] + bv;
          if (MODE == M_RELU) v = fmaxf(v, 0.0f);
          outBF[(long long)bz * sOb + (long long)(mt + r) * N + nt] = f2bf(v);
        }
      } else if (MODE == M_SCBF) {
#pragma unroll
        for (int r = 0; r < 4; ++r)
          outBF[(long long)bz * sOb + (long long)(mt + r) * N + nt] = f2bf(d[r] * scale);
      } else if (MODE == M_RESID) {
        const float bv = bias[nt];
#pragma unroll
        for (int r = 0; r < 4; ++r) {
          const long long idx = (long long)(mt + r) * N + nt;
          outF[idx] = resid[idx] + d[r] + bv;
        }
      } else if (MODE == M_QKV) {
        // N=3072 packed: seg 0 -> Q [32768,1024], seg 1 -> K [32768,1024],
        // seg 2 -> V transposed per batch: vT[b][d][s].
        const int seg = n0 >> 10;         // block-uniform (1024 % 128 == 0)
        const int ntl = nt - (seg << 10);
        const float bv = bias[nt];
        if (seg < 2) {
          unsigned short* dst = outBF + (long long)seg * 33554432LL;
#pragma unroll
          for (int r = 0; r < 4; ++r)
            dst[(long long)(mt + r) * 1024 + ntl] = f2bf(d[r] + bv);
        } else {
          unsigned short* dst = outBF + 2LL * 33554432LL;
          us4 pk;
#pragma unroll
          for (int r = 0; r < 4; ++r) pk[r] = f2bf(d[r] + bv);
          const int b = mt >> 10;
          const int s = mt & 1023;
          *(us4*)&dst[(long long)b * 1048576 + (long long)ntl * 1024 + s] = pk;
        }
      }
    }
  }
}

// LayerNorm over rows of 1024. EMBED=1: v = 32*x + pe written to x1out; else read xin.
template<int EMBED>
__global__ __launch_bounds__(256) void ln_kernel(
    const float* __restrict__ xin, const float* __restrict__ pe,
    float* __restrict__ x1out,
    const float* __restrict__ g, const float* __restrict__ bb,
    unsigned short* __restrict__ hout)
{
  __shared__ float red[8];
  const long long row = blockIdx.x;
  const int t = threadIdx.x, lane = t & 63, w = t >> 6;
  float4 v = *(const float4*)(xin + row * 1024 + t * 4);
  if (EMBED) {
    const int s = (int)(row & 1023);
    float4 p = *(const float4*)(pe + (long long)s * 1024 + t * 4);
    v.x = 32.0f * v.x + p.x;
    v.y = 32.0f * v.y + p.y;
    v.z = 32.0f * v.z + p.z;
    v.w = 32.0f * v.w + p.w;
    *(float4*)(x1out + row * 1024 + t * 4) = v;
  }
  float sum = v.x + v.y + v.z + v.w;
  float sq  = v.x * v.x + v.y * v.y + v.z * v.z + v.w * v.w;
#pragma unroll
  for (int off = 32; off > 0; off >>= 1) {
    sum += __shfl_down(sum, off, 64);
    sq  += __shfl_down(sq,  off, 64);
  }
  if (lane == 0) { red[w] = sum; red[4 + w] = sq; }
  __syncthreads();
  sum = red[0] + red[1] + red[2] + red[3];
  sq  = red[4] + red[5] + red[6] + red[7];
  const float mu  = sum * (1.0f / 1024.0f);
  const float var = sq * (1.0f / 1024.0f) - mu * mu;
  const float rs  = rsqrtf(var + 1e-5f);
  float4 gg = *(const float4*)(g + t * 4);
  float4 bv = *(const float4*)(bb + t * 4);
  us4 h;
  h[0] = f2bf((v.x - mu) * rs * gg.x + bv.x);
  h[1] = f2bf((v.y - mu) * rs * gg.y + bv.y);
  h[2] = f2bf((v.z - mu) * rs * gg.z + bv.z);
  h[3] = f2bf((v.w - mu) * rs * gg.w + bv.w);
  *(us4*)(hout + row * 1024 + t * 4) = h;
}

// Softmax over rows of 1024: reads bf16 scores, writes fp32 w (d_out) + bf16 w.
__global__ __launch_bounds__(256) void softmax_kernel(
    const unsigned short* __restrict__ sbf,
    float* __restrict__ wout, unsigned short* __restrict__ wbf)
{
  __shared__ float red[8];
  const long long row = blockIdx.x;
  const int t = threadIdx.x, lane = t & 63, w = t >> 6;
  us4 sv = *(const us4*)(sbf + row * 1024 + t * 4);
  float4 v;
  v.x = bf2f(sv[0]); v.y = bf2f(sv[1]); v.z = bf2f(sv[2]); v.w = bf2f(sv[3]);
  float mx = fmaxf(fmaxf(v.x, v.y), fmaxf(v.z, v.w));
#pragma unroll
  for (int off = 32; off > 0; off >>= 1) mx = fmaxf(mx, __shfl_down(mx, off, 64));
  if (lane == 0) red[w] = mx;
  __syncthreads();
  mx = fmaxf(fmaxf(red[0], red[1]), fmaxf(red[2], red[3]));
  __syncthreads();
  const float e0 = __expf(v.x - mx), e1 = __expf(v.y - mx);
  const float e2 = __expf(v.z - mx), e3 = __expf(v.w - mx);
  float s = e0 + e1 + e2 + e3;
#pragma unroll
  for (int off = 32; off > 0; off >>= 1) s += __shfl_down(s, off, 64);
  if (lane == 0) red[w] = s;
  __syncthreads();
  s = red[0] + red[1] + red[2] + red[3];
  const float inv = 1.0f / s;
  float4 o; o.x = e0 * inv; o.y = e1 * inv; o.z = e2 * inv; o.w = e3 * inv;
  *(float4*)(wout + row * 1024 + t * 4) = o;
  us4 ob;
  ob[0] = f2bf(o.x); ob[1] = f2bf(o.y); ob[2] = f2bf(o.z); ob[3] = f2bf(o.w);
  *(us4*)(wbf + row * 1024 + t * 4) = ob;
}

// One prep kernel: bf16-convert all 6 weights (QKV packed [3072,1024]) + pack QKV bias.
__global__ __launch_bounds__(256) void prep_kernel(
    const float* __restrict__ Wq, const float* __restrict__ Wk, const float* __restrict__ Wv,
    const float* __restrict__ Wo, const float* __restrict__ W1, const float* __restrict__ W2,
    const float* __restrict__ bq, const float* __restrict__ bk, const float* __restrict__ bv,
    unsigned short* __restrict__ qkvw, unsigned short* __restrict__ Wo_bf,
    unsigned short* __restrict__ W1_bf, unsigned short* __restrict__ W2_bf,
    float* __restrict__ qkvb)
{
  const int y = blockIdx.y;
  const long long i = blockIdx.x * 256 + threadIdx.x;   // quad index, < 262144
  if (y == 6) {
    if (i < 768) {
      const float* src = (i < 256) ? bq : (i < 512) ? bk : bv;
      float4 v = *(const float4*)(src + (i & 255) * 4);
      *(float4*)(qkvb + i * 4) = v;
    }
    return;
  }
  const float* src;
  unsigned short* dst;
  switch (y) {
    case 0: src = Wq; dst = qkvw;            break;
    case 1: src = Wk; dst = qkvw + 1048576;  break;
    case 2: src = Wv; dst = qkvw + 2097152;  break;
    case 3: src = Wo; dst = Wo_bf;           break;
    case 4: src = W1; dst = W1_bf;           break;
    default: src = W2; dst = W2_bf;          break;
  }
  float4 v = *(const float4*)(src + i * 4);
  us4 o;
  o[0] = f2bf(v.x); o[1] = f2bf(v.y); o[2] = f2bf(v.z); o[3] = f2bf(v.w);
  *(us4*)(dst + i * 4) = o;
}

// logits[b,o] = x[b, s=0, :] . Wc[o,:] + bc[o]; 64 blocks, fp32.
__global__ __launch_bounds__(256) void logits_kernel(
    const float* __restrict__ x, const float* __restrict__ Wc,
    const float* __restrict__ bc, float* __restrict__ out)
{
  __shared__ float red[4];
  const int blk = blockIdx.x;           // b*2 + o
  const int b = blk >> 1, o = blk & 1;
  const int t = threadIdx.x, lane = t & 63, w = t >> 6;
  const float* xr = x + (long long)b * 1048576;
  const float* wr = Wc + o * 1024;
  float4 xv = *(const float4*)(xr + t * 4);
  float4 wv = *(const float4*)(wr + t * 4);
  float s = xv.x * wv.x + xv.y * wv.y + xv.z * wv.z + xv.w * wv.w;
#pragma unroll
  for (int off = 32; off > 0; off >>= 1) s += __shfl_down(s, off, 64);
  if (lane == 0) red[w] = s;
  __syncthreads();
  if (t == 0) out[blk] = red[0] + red[1] + red[2] + red[3] + bc[o];
}

extern "C" void kernel_launch(void* const* d_in, const int* in_sizes, int n_in,
                              void* d_out, int out_size, void* d_ws, size_t ws_size,
                              hipStream_t stream)
{
  const float* x    = (const float*)d_in[0];
  const float* pe   = (const float*)d_in[1];
  const float* ln1g = (const float*)d_in[2];
  const float* ln1b = (const float*)d_in[3];
  const float* Wq   = (const float*)d_in[4];
  const float* bq   = (const float*)d_in[5];
  const float* Wk   = (const float*)d_in[6];
  const float* bk   = (const float*)d_in[7];
  const float* Wv   = (const float*)d_in[8];
  const float* bv   = (const float*)d_in[9];
  const float* Wo   = (const float*)d_in[10];
  const float* bo   = (const float*)d_in[11];
  const float* ln2g = (const float*)d_in[12];
  const float* ln2b = (const float*)d_in[13];
  const float* W1   = (const float*)d_in[14];
  const float* b1   = (const float*)d_in[15];
  const float* W2   = (const float*)d_in[16];
  const float* b2   = (const float*)d_in[17];
  const float* Wc   = (const float*)d_in[18];
  const float* bc   = (const float*)d_in[19];
  float* out = (float*)d_out;

  // Workspace layout (~400 MiB):
  //   xbuf   128 MiB fp32 residual stream
  //   h_bf    64 MiB (LN out; reused as bf16 scores scratch)
  //   q_bf    64 MiB (QKV seg0; reused as attn out)
  //   k_bf    64 MiB (QKV seg1; reused as bf16 softmax weights)
  //   vT_bf   64 MiB (QKV seg2, transposed; reused as ff1)
  //   weights: QKV packed 6 MiB + Wo/W1/W2 2 MiB each + qkvb 12 KiB
  char* ws = (char*)d_ws;
  float*          xbuf  = (float*)ws;
  unsigned short* h_bf  = (unsigned short*)(ws + 134217728LL);
  unsigned short* q_bf  = (unsigned short*)(ws + 134217728LL + 1 * 67108864LL);
  unsigned short* k_bf  = (unsigned short*)(ws + 134217728LL + 2 * 67108864LL);
  unsigned short* vT_bf = (unsigned short*)(ws + 134217728LL + 3 * 67108864LL);
  unsigned short* wts   = (unsigned short*)(ws + 134217728LL + 4 * 67108864LL);
  unsigned short* QKV_bf = wts;                       // [3072,1024]
  unsigned short* Wo_bf  = wts + 3LL * 1048576;
  unsigned short* W1_bf  = wts + 4LL * 1048576;
  unsigned short* W2_bf  = wts + 5LL * 1048576;
  float*          qkvb   = (float*)(wts + 6LL * 1048576);  // [3072]
  unsigned short* sc_bf   = h_bf;
  unsigned short* w_bf    = k_bf;
  unsigned short* attn_bf = q_bf;
  unsigned short* ff1_bf  = vT_bf;

  const dim3 blk(256);
  prep_kernel<<<dim3(1024, 7), blk, 0, stream>>>(Wq, Wk, Wv, Wo, W1, W2, bq, bk, bv,
                                                 QKV_bf, Wo_bf, W1_bf, W2_bf, qkvb);

  const dim3 gQKV(24, 256, 1);   // N=3072, M=32768
  const dim3 gProj(8, 256, 1);   // N=1024, M=32768
  const dim3 gAttn(8, 8, 32);    // N=M=1024, batch=32

  for (int blkI = 0; blkI < 2; ++blkI) {
    float* wslot = out + 64 + (long long)blkI * 33554432LL;

    if (blkI == 0)
      ln_kernel<1><<<32768, blk, 0, stream>>>(x, pe, xbuf, ln1g, ln1b, h_bf);
    else
      ln_kernel<0><<<32768, blk, 0, stream>>>(xbuf, nullptr, nullptr, ln1g, ln1b, h_bf);

    gemm_bt<M_QKV><<<gQKV, blk, 0, stream>>>(h_bf, 0, QKV_bf, 0, qkvb, nullptr,
                                             nullptr, q_bf, 0, 3072, 1024, 1.0f);

    gemm_bt<M_SCBF><<<gAttn, blk, 0, stream>>>(q_bf, 1048576, k_bf, 1048576, nullptr,
                                               nullptr, nullptr, sc_bf, 1048576,
                                               1024, 1024, 0.03125f);
    softmax_kernel<<<32768, blk, 0, stream>>>(sc_bf, wslot, w_bf);

    gemm_bt<M_BF16><<<gAttn, blk, 0, stream>>>(w_bf, 1048576, vT_bf, 1048576, nullptr,
                                               nullptr, nullptr, attn_bf, 1048576,
                                               1024, 1024, 1.0f);
    gemm_bt<M_RESID><<<gProj, blk, 0, stream>>>(attn_bf, 0, Wo_bf, 0, bo, xbuf,
                                                xbuf, nullptr, 0, 1024, 1024, 1.0f);

    ln_kernel<0><<<32768, blk, 0, stream>>>(xbuf, nullptr, nullptr, ln2g, ln2b, h_bf);
    gemm_bt<M_RELU><<<gProj, blk, 0, stream>>>(h_bf, 0, W1_bf, 0, b1, nullptr,
                                               nullptr, ff1_bf, 0, 1024, 1024, 1.0f);
    gemm_bt<M_RESID><<<gProj, blk, 0, stream>>>(ff1_bf, 0, W2_bf, 0, b2, xbuf,
                                                xbuf, nullptr, 0, 1024, 1024, 1.0f);
  }

  logits_kernel<<<64, blk, 0, stream>>>(xbuf, Wc, bc, out);
  (void)in_sizes; (void)n_in; (void)out_size; (void)ws_size;
}